// Round 5
// baseline (406.790 us; speedup 1.0000x reference)
//
#include <hip/hip_runtime.h>
#include <hip/hip_bf16.h>

#define B_ 32
#define S_ 1024
#define C_ 256
#define SP 1040   // 8 left halo + 1024 + 8 right halo rows per batch

typedef float f32x4  __attribute__((ext_vector_type(4)));
typedef float f32x16 __attribute__((ext_vector_type(16)));
typedef __bf16 bf16x8 __attribute__((ext_vector_type(8)));
typedef __bf16 bf16x4 __attribute__((ext_vector_type(4)));

// ---------------------------------------------------------------------------
// Repack W[co][ci][k] fp32 -> bf16 for 32x32x16 MFMA A-frags.
// dst bits: e=i&7, co=(i>>3)&255, h=(i>>11)&1, ks=(i>>12)&1, c32=(i>>13)&7, j=i>>16
// ci = c32*32 + ks*16 + h*8 + e
// A-frag load (lane l, step s=j*8+c32): 16B at (s*4 + ks*2 + (l>>5))*2048 + co*8
// ---------------------------------------------------------------------------
__global__ __launch_bounds__(256) void wcvt_kernel(const float* __restrict__ w,
                                                   __hip_bfloat16* __restrict__ wb,
                                                   int k, int n) {
    int i = blockIdx.x * 256 + threadIdx.x;
    if (i >= n) return;
    int e   = i & 7;
    int co  = (i >> 3) & 255;
    int hh  = (i >> 11) & 1;
    int ks  = (i >> 12) & 1;
    int c32 = (i >> 13) & 7;
    int j   = i >> 16;
    int ci  = c32 * 32 + ks * 16 + hh * 8 + e;
    wb[i] = __float2bfloat16(w[(co * 256 + ci) * k + j]);
}

// ---------------------------------------------------------------------------
// prep v3: one wave processes FOUR (b,t) rows (chains interleave for ILP).
//   GATE: score = sigmoid(0.5*(y0+y1) + 0.1*max(y0,y1)), x *= (1+score)
//   NORM: ChannelNorm (unbiased var) + ReLU -> bf16 into haloed y buffer
//   !NORM: write gated fp32 row to d_out
// ---------------------------------------------------------------------------
template<bool GATE, bool NORM, bool BF16IN>
__global__ __launch_bounds__(256) void prep_kernel(const void* __restrict__ in_,
                                                   const float* __restrict__ fc,
                                                   const float* __restrict__ cw,
                                                   const float* __restrict__ cb,
                                                   __hip_bfloat16* __restrict__ yout,
                                                   float* __restrict__ fout) {
    const int lane = threadIdx.x & 63;
    const int rid0 = (blockIdx.x * 4 + (threadIdx.x >> 6)) * 4;

    f32x4 xv[4];
    int bi[4], ti[4];
    bool live[4];

#pragma unroll
    for (int rr = 0; rr < 4; ++rr) {
        int rid = rid0 + rr;
        if constexpr (NORM) {
            int b = rid / SP;
            int r = rid - b * SP;
            int t = r - 8;
            bi[rr] = b; ti[rr] = t;
            live[rr] = (t >= 0) && (t < S_);
            if (!live[rr])
                *(ushort4*)(yout + (size_t)rid * C_ + lane * 4) = make_ushort4(0, 0, 0, 0);
        } else {
            bi[rr] = rid >> 10; ti[rr] = rid & 1023; live[rr] = true;
        }
    }

#pragma unroll
    for (int rr = 0; rr < 4; ++rr) {
        if (live[rr]) {
            size_t idx = ((size_t)(bi[rr] * S_ + ti[rr])) * C_ + lane * 4;
            if constexpr (BF16IN) {
                bf16x4 hv = *(const bf16x4*)((const __hip_bfloat16*)in_ + idx);
                xv[rr].x = (float)hv[0]; xv[rr].y = (float)hv[1];
                xv[rr].z = (float)hv[2]; xv[rr].w = (float)hv[3];
            } else {
                xv[rr] = *(const f32x4*)((const float*)in_ + idx);
            }
        } else {
            xv[rr] = f32x4{0.f, 0.f, 0.f, 0.f};
        }
    }

    if constexpr (GATE) {
        f32x4 f0 = *(const f32x4*)(fc + lane * 4);
        f32x4 f1 = *(const f32x4*)(fc + C_ + lane * 4);
        float p[4], q[4];
#pragma unroll
        for (int rr = 0; rr < 4; ++rr) {
            p[rr] = xv[rr].x * f0.x + xv[rr].y * f0.y + xv[rr].z * f0.z + xv[rr].w * f0.w;
            q[rr] = xv[rr].x * f1.x + xv[rr].y * f1.y + xv[rr].z * f1.z + xv[rr].w * f1.w;
        }
#pragma unroll
        for (int m = 32; m >= 1; m >>= 1) {
#pragma unroll
            for (int rr = 0; rr < 4; ++rr) {
                p[rr] += __shfl_xor(p[rr], m, 64);
                q[rr] += __shfl_xor(q[rr], m, 64);
            }
        }
#pragma unroll
        for (int rr = 0; rr < 4; ++rr) {
            float s = 0.5f * (p[rr] + q[rr]) + 0.1f * fmaxf(p[rr], q[rr]);
            float g = 1.0f + 1.0f / (1.0f + expf(-s));
            xv[rr].x *= g; xv[rr].y *= g; xv[rr].z *= g; xv[rr].w *= g;
        }
    }

    if constexpr (NORM) {
        float s1[4], s2[4];
#pragma unroll
        for (int rr = 0; rr < 4; ++rr) {
            s1[rr] = xv[rr].x + xv[rr].y + xv[rr].z + xv[rr].w;
            s2[rr] = xv[rr].x * xv[rr].x + xv[rr].y * xv[rr].y
                   + xv[rr].z * xv[rr].z + xv[rr].w * xv[rr].w;
        }
#pragma unroll
        for (int m = 32; m >= 1; m >>= 1) {
#pragma unroll
            for (int rr = 0; rr < 4; ++rr) {
                s1[rr] += __shfl_xor(s1[rr], m, 64);
                s2[rr] += __shfl_xor(s2[rr], m, 64);
            }
        }
        f32x4 w4 = *(const f32x4*)(cw + lane * 4);
        f32x4 b4 = *(const f32x4*)(cb + lane * 4);
#pragma unroll
        for (int rr = 0; rr < 4; ++rr) {
            if (!live[rr]) continue;
            float mean = s1[rr] * (1.0f / 256.0f);
            float var  = fmaxf((s2[rr] - 256.0f * mean * mean) * (1.0f / 255.0f), 0.0f);
            float inv  = rsqrtf(var + 1e-5f);
            union { ushort4 u; __hip_bfloat16 e[4]; } o;
            o.e[0] = __float2bfloat16(fmaxf(0.0f, (xv[rr].x - mean) * inv * w4.x + b4.x));
            o.e[1] = __float2bfloat16(fmaxf(0.0f, (xv[rr].y - mean) * inv * w4.y + b4.y));
            o.e[2] = __float2bfloat16(fmaxf(0.0f, (xv[rr].z - mean) * inv * w4.z + b4.z));
            o.e[3] = __float2bfloat16(fmaxf(0.0f, (xv[rr].w - mean) * inv * w4.w + b4.w));
            *(ushort4*)(yout + (size_t)(rid0 + rr) * C_ + lane * 4) = o.u;
        }
    } else {
#pragma unroll
        for (int rr = 0; rr < 4; ++rr) {
            *(f32x4*)(fout + ((size_t)(bi[rr] * S_ + ti[rr])) * C_ + lane * 4) = xv[rr];
        }
    }
}

// ---------------------------------------------------------------------------
// conv v3: block = 8 waves (512 thr), tile 128 co x 256 t x 1 batch, grid 256
// (= 32 b x 4 tt x 2 cg, cg innermost). Waves: 2 co-groups x 4 t-quarters;
// wave = 64co x 64t, mfma_f32_32x32x16_bf16. Per-CU unique-A L2 demand:
// 2 cg x 4KB per 128 SIMD-cyc step = 64 B/cyc (vs ~56 available; was 125).
// Activations in LDS [264 rows][256 ci] bf16, 16B-slot swizzle ^(r&7).
// Per-j __syncthreads keeps the 4 waves/co-group within an L1-sized window.
// ---------------------------------------------------------------------------
template<int KS, int PAD, int LVALID>
__global__ __launch_bounds__(512, 2) void conv_kernel(const __hip_bfloat16* __restrict__ y,
                                                      const __hip_bfloat16* __restrict__ wb,
                                                      __hip_bfloat16* __restrict__ hout) {
    __shared__ alignas(16) __hip_bfloat16 ly[264 * 256];   // 135,168 B
    const int tid  = threadIdx.x;
    const int lane = tid & 63;
    const int wv   = tid >> 6;
    const int cg   = blockIdx.x & 1;
    const int tt   = (blockIdx.x >> 1) & 3;
    const int b    = blockIdx.x >> 3;
    const int t0   = tt << 8;

    // stage 264 rows x 256 ci (rows t0-PAD .. t0-PAD+263 in padded coords)
    {
        const __hip_bfloat16* ybase = y + ((size_t)(b * SP + 8 + t0 - PAD)) * C_;
#pragma unroll
        for (int c = 0; c < 17; ++c) {
            int u = c * 512 + tid;              // 16B unit, 8448 total
            if (u < 8448) {
                int r = u >> 5, s = u & 31;
                bf16x8 v = *(const bf16x8*)(ybase + (size_t)r * C_ + ((s ^ (r & 7)) << 3));
                *(bf16x8*)(ly + (size_t)u * 8) = v;
            }
        }
    }
    __syncthreads();

    const int cog = wv & 1;                 // co-group within block
    const int tq  = wv >> 1;                // t-quarter
    const int l31 = lane & 31;
    const int hh  = lane >> 5;
    const int co_base = cg * 128 + cog * 64;

    f32x16 acc[2][2];
#pragma unroll
    for (int mf = 0; mf < 2; ++mf)
#pragma unroll
        for (int nf = 0; nf < 2; ++nf)
#pragma unroll
            for (int e = 0; e < 16; ++e)
                acc[mf][nf][e] = 0.0f;

    const __hip_bfloat16* abase = wb + (size_t)hh * 2048 + (size_t)(co_base + l31) * 8;

    for (int j = 0; j < KS; ++j) {
        if (j) __syncthreads();             // keep co-group wave quartet in L1 window
#pragma unroll 4
        for (int c32 = 0; c32 < 8; ++c32) {
            const int s = j * 8 + c32;
            bf16x8 a[2][2], bf[2][2];
#pragma unroll
            for (int ks = 0; ks < 2; ++ks)
#pragma unroll
                for (int mf = 0; mf < 2; ++mf)
                    a[ks][mf] = *(const bf16x8*)(abase + (size_t)(s * 4 + ks * 2) * 2048 + mf * 256);
#pragma unroll
            for (int ks = 0; ks < 2; ++ks)
#pragma unroll
                for (int nf = 0; nf < 2; ++nf) {
                    int r   = tq * 64 + nf * 32 + l31 + j;
                    int ci8 = c32 * 4 + ks * 2 + hh;
                    bf[ks][nf] = *(const bf16x8*)(ly + (size_t)r * 256 + ((ci8 ^ (r & 7)) << 3));
                }
#pragma unroll
            for (int ks = 0; ks < 2; ++ks)
#pragma unroll
                for (int mf = 0; mf < 2; ++mf)
#pragma unroll
                    for (int nf = 0; nf < 2; ++nf)
                        acc[mf][nf] = __builtin_amdgcn_mfma_f32_32x32x16_bf16(
                            a[ks][mf], bf[ks][nf], acc[mf][nf], 0, 0, 0);
        }
    }

    // epilogue: D col = lane&31 -> t, row = (reg&3) + 8*(reg>>2) + 4*(lane>>5) -> co
    __hip_bfloat16* hb = hout + ((size_t)(b * S_ + t0 + tq * 64)) * C_ + co_base;
#pragma unroll
    for (int nf = 0; nf < 2; ++nf) {
        int tl = nf * 32 + l31;
        bool zout = (LVALID < S_) && (t0 + tq * 64 + tl >= LVALID);
#pragma unroll
        for (int mf = 0; mf < 2; ++mf) {
#pragma unroll
            for (int r4 = 0; r4 < 4; ++r4) {
                int co = mf * 32 + r4 * 8 + hh * 4;
                union { ushort4 u; __hip_bfloat16 e[4]; } o;
#pragma unroll
                for (int q = 0; q < 4; ++q) {
                    float v = zout ? 0.0f : acc[mf][nf][r4 * 4 + q];
                    o.e[q] = __float2bfloat16(v);
                }
                *(ushort4*)(hb + (size_t)tl * C_ + co) = o.u;
            }
        }
    }
}

// ---------------------------------------------------------------------------
extern "C" void kernel_launch(void* const* d_in, const int* in_sizes, int n_in,
                              void* d_out, int out_size, void* d_ws, size_t ws_size,
                              hipStream_t stream) {
    const float* inputs = (const float*)d_in[0];
    const float* cw[5] = { (const float*)d_in[1],  (const float*)d_in[4],
                           (const float*)d_in[7],  (const float*)d_in[10],
                           (const float*)d_in[13] };
    const float* cb[5] = { (const float*)d_in[2],  (const float*)d_in[5],
                           (const float*)d_in[8],  (const float*)d_in[11],
                           (const float*)d_in[14] };
    const float* Wf[5] = { (const float*)d_in[3],  (const float*)d_in[6],
                           (const float*)d_in[9],  (const float*)d_in[12],
                           (const float*)d_in[15] };
    const float* fc = (const float*)d_in[16];

    char* ws = (char*)d_ws;
    __hip_bfloat16* y = (__hip_bfloat16*)ws;              // 32*1040*256*2 = 17,039,360 B
    __hip_bfloat16* h = (__hip_bfloat16*)(ws + 17039360); // 32*1024*256*2 = 16,777,216 B
    __hip_bfloat16* wb[5];
    size_t off = 17039360 + 16777216;
    for (int l = 0; l < 5; ++l) {
        wb[l] = (__hip_bfloat16*)(ws + off);
        off += (size_t)(l + 4) * 65536 * 2;
    }
    float* out = (float*)d_out;

    for (int l = 0; l < 5; ++l) {
        int k = l + 4, n = k * 65536;
        wcvt_kernel<<<(n + 255) / 256, 256, 0, stream>>>(Wf[l], wb[l], k, n);
    }

    const int GN = (B_ * SP) / 16;   // 2080 blocks, 16 rows each (4 waves x 4 rows)
    const int GO = (B_ * S_) / 16;   // 2048 blocks for the final gate
    prep_kernel<false, true, false><<<GN, 256, 0, stream>>>(inputs, fc, cw[0], cb[0], y, nullptr);
    conv_kernel<4, 1, 1023><<<256, 512, 0, stream>>>(y, wb[0], h);
    prep_kernel<true, true, true><<<GN, 256, 0, stream>>>(h, fc, cw[1], cb[1], y, nullptr);
    conv_kernel<5, 2, 1024><<<256, 512, 0, stream>>>(y, wb[1], h);
    prep_kernel<true, true, true><<<GN, 256, 0, stream>>>(h, fc, cw[2], cb[2], y, nullptr);
    conv_kernel<6, 2, 1023><<<256, 512, 0, stream>>>(y, wb[2], h);
    prep_kernel<true, true, true><<<GN, 256, 0, stream>>>(h, fc, cw[3], cb[3], y, nullptr);
    conv_kernel<7, 3, 1024><<<256, 512, 0, stream>>>(y, wb[3], h);
    prep_kernel<true, true, true><<<GN, 256, 0, stream>>>(h, fc, cw[4], cb[4], y, nullptr);
    conv_kernel<8, 3, 1023><<<256, 512, 0, stream>>>(y, wb[4], h);
    prep_kernel<true, false, true><<<GO, 256, 0, stream>>>(h, fc, nullptr, nullptr, nullptr, out);
}

// Round 6
// 383.443 us; speedup vs baseline: 1.0609x; 1.0609x over previous
//
#include <hip/hip_runtime.h>
#include <hip/hip_bf16.h>

#define B_ 32
#define S_ 1024
#define C_ 256
#define SP 1040   // 8 left halo + 1024 + 8 right halo rows per batch

typedef float f32x4  __attribute__((ext_vector_type(4)));
typedef float f32x16 __attribute__((ext_vector_type(16)));
typedef __bf16 bf16x8 __attribute__((ext_vector_type(8)));

// ---------------------------------------------------------------------------
// Repack all 5 layers' W[co][ci][k] fp32 -> bf16, contiguous dst.
// dst bits (within layer): e=i&7, co=(i>>3)&255, hh=(i>>11)&1, ks=(i>>12)&1,
// c32=(i>>13)&7, j=i>>16;  ci = c32*32+ks*16+hh*8+e
// ---------------------------------------------------------------------------
__global__ __launch_bounds__(256) void wcvt_all(
        const float* __restrict__ w4, const float* __restrict__ w5,
        const float* __restrict__ w6, const float* __restrict__ w7,
        const float* __restrict__ w8, __hip_bfloat16* __restrict__ wb) {
    int i = blockIdx.x * 256 + threadIdx.x;   // grid exact: 1966080 / 256
    const float* src; int base, k;
    if      (i <  262144) { src = w4; base = 0;       k = 4; }
    else if (i <  589824) { src = w5; base = 262144;  k = 5; }
    else if (i <  983040) { src = w6; base = 589824;  k = 6; }
    else if (i < 1441792) { src = w7; base = 983040;  k = 7; }
    else                  { src = w8; base = 1441792; k = 8; }
    int ii = i - base;
    int e = ii & 7, co = (ii >> 3) & 255, hh = (ii >> 11) & 1;
    int ks = (ii >> 12) & 1, c32 = (ii >> 13) & 7, j = ii >> 16;
    int ci = c32 * 32 + ks * 16 + hh * 8 + e;
    wb[i] = __float2bfloat16(src[(co * 256 + ci) * k + j]);
}

// Zero the 16 halo rows of a haloed y buffer (32 b x 16 rows x 256 ch).
__global__ __launch_bounds__(256) void zeroh_kernel(__hip_bfloat16* __restrict__ y) {
    int i = blockIdx.x * 256 + threadIdx.x;   // 16384 threads
    int b = i >> 9, rr = (i >> 5) & 15, s = i & 31;
    int row = (rr < 8) ? rr : (1024 + rr);    // 0..7, 1032..1039
    uint4 z = make_uint4(0, 0, 0, 0);
    *(uint4*)(y + ((size_t)(b * SP + row)) * C_ + s * 8) = z;
}

// ---------------------------------------------------------------------------
// prep0: ChannelNorm + ReLU on fp32 input -> bf16 haloed y. 2 rows/wave,
// 32 lanes x 8ch per row; 5-level shfl reduce (stays within 32-lane half).
// ---------------------------------------------------------------------------
__global__ __launch_bounds__(256) void prep0_kernel(const float* __restrict__ in,
                                                    const float* __restrict__ cw,
                                                    const float* __restrict__ cb,
                                                    __hip_bfloat16* __restrict__ yout) {
    const int lane = threadIdx.x & 63;
    const int sl   = lane & 31;
    const int rid  = (blockIdx.x * 4 + (threadIdx.x >> 6)) * 2 + (lane >> 5);
    const int b = rid / SP;
    const int t = (rid - b * SP) - 8;
    __hip_bfloat16* drow = yout + (size_t)rid * C_ + sl * 8;
    if (t < 0 || t >= S_) { *(uint4*)drow = make_uint4(0, 0, 0, 0); return; }

    const float* row = in + ((size_t)(b * S_ + t)) * C_ + sl * 8;
    f32x4 x0 = *(const f32x4*)row;
    f32x4 x1 = *(const f32x4*)(row + 4);
    float s1 = x0.x + x0.y + x0.z + x0.w + x1.x + x1.y + x1.z + x1.w;
    float s2 = x0.x*x0.x + x0.y*x0.y + x0.z*x0.z + x0.w*x0.w
             + x1.x*x1.x + x1.y*x1.y + x1.z*x1.z + x1.w*x1.w;
#pragma unroll
    for (int m = 16; m >= 1; m >>= 1) {
        s1 += __shfl_xor(s1, m, 64);
        s2 += __shfl_xor(s2, m, 64);
    }
    float mean = s1 * (1.0f / 256.0f);
    float var  = fmaxf((s2 - 256.0f * mean * mean) * (1.0f / 255.0f), 0.0f);
    float inv  = rsqrtf(var + 1e-5f);
    f32x4 w0 = *(const f32x4*)(cw + sl * 8);
    f32x4 w1 = *(const f32x4*)(cw + sl * 8 + 4);
    f32x4 b0 = *(const f32x4*)(cb + sl * 8);
    f32x4 b1 = *(const f32x4*)(cb + sl * 8 + 4);
    union { uint4 u; __hip_bfloat16 e[8]; } o;
    o.e[0] = __float2bfloat16(fmaxf(0.f, (x0.x - mean)*inv*w0.x + b0.x));
    o.e[1] = __float2bfloat16(fmaxf(0.f, (x0.y - mean)*inv*w0.y + b0.y));
    o.e[2] = __float2bfloat16(fmaxf(0.f, (x0.z - mean)*inv*w0.z + b0.z));
    o.e[3] = __float2bfloat16(fmaxf(0.f, (x0.w - mean)*inv*w0.w + b0.w));
    o.e[4] = __float2bfloat16(fmaxf(0.f, (x1.x - mean)*inv*w1.x + b1.x));
    o.e[5] = __float2bfloat16(fmaxf(0.f, (x1.y - mean)*inv*w1.y + b1.y));
    o.e[6] = __float2bfloat16(fmaxf(0.f, (x1.z - mean)*inv*w1.z + b1.z));
    o.e[7] = __float2bfloat16(fmaxf(0.f, (x1.w - mean)*inv*w1.w + b1.w));
    *(uint4*)drow = o.u;
}

// ---------------------------------------------------------------------------
// conv_fused: conv + gate + (norm+relu for next layer | fp32 final out).
// Block = 4 waves (256 thr) = 2 cog x 2 tq; wave = 128co x 64t (mf=4, nf=2),
// mfma_f32_32x32x16_bf16, R = 1 B-read per 4 MFMA (LDS cap 67% vs 33% before).
// Explicit 2-stage software pipeline (static stage indices). Grid = 32b x 8tt.
// Epilogue: per-lane fc/cw/cb gathers over acc + shfl(32) + 2KB LDS cross-cog
// reductions -> gate -> channel-norm -> bf16 y_next (or fp32 d_out for LAST).
// ---------------------------------------------------------------------------
template<int KS, int PAD, int LVALID, bool LAST>
__global__ __launch_bounds__(256, 2) void conv_fused(
        const __hip_bfloat16* __restrict__ y,
        const __hip_bfloat16* __restrict__ wb,
        __hip_bfloat16* __restrict__ ynext,
        float* __restrict__ fout,
        const float* __restrict__ fc,
        const float* __restrict__ cwn,
        const float* __restrict__ cbn) {
    __shared__ alignas(16) __hip_bfloat16 ly[135 * 256];   // 69,120 B
    __shared__ float redpq[128][4];
    __shared__ float redss[128][4];
    const int tid  = threadIdx.x;
    const int lane = tid & 63;
    const int wv   = tid >> 6;
    const int tt   = blockIdx.x & 7;
    const int b    = blockIdx.x >> 3;
    const int t0   = tt << 7;

    // stage 135 rows x 256 ci (padded rows t0-PAD .. t0-PAD+134), swizzle ^(r&7)
    {
        const __hip_bfloat16* yb = y + ((size_t)(b * SP + 8 + t0 - PAD)) * C_;
#pragma unroll
        for (int c = 0; c < 17; ++c) {
            int u = c * 256 + tid;
            if (u < 4320) {
                int r = u >> 5, s2 = u & 31;
                *(bf16x8*)(ly + (size_t)u * 8) =
                    *(const bf16x8*)(yb + (size_t)r * C_ + ((s2 ^ (r & 7)) << 3));
            }
        }
    }
    __syncthreads();

    const int cog = wv & 1;
    const int tq  = wv >> 1;
    const int l31 = lane & 31;
    const int hh  = lane >> 5;

    f32x16 acc[4][2];
#pragma unroll
    for (int mf = 0; mf < 4; ++mf)
#pragma unroll
        for (int nf = 0; nf < 2; ++nf)
#pragma unroll
            for (int e = 0; e < 16; ++e)
                acc[mf][nf][e] = 0.0f;

    const __hip_bfloat16* abase = wb + (size_t)hh * 2048 + (size_t)(cog * 128 + l31) * 8;
    const int rbase = tq * 64 + l31;

    bf16x8 aF[2][2][4], bF[2][2][2];

#define LOADS(ST, S) { \
    const int jj_ = (S) >> 3, cc_ = (S) & 7; \
    _Pragma("unroll") for (int ks = 0; ks < 2; ++ks) { \
        _Pragma("unroll") for (int mf = 0; mf < 4; ++mf) \
            aF[ST][ks][mf] = *(const bf16x8*)(abase + (size_t)((S) * 4 + ks * 2) * 2048 + mf * 256); \
        _Pragma("unroll") for (int nf = 0; nf < 2; ++nf) { \
            int r_ = rbase + nf * 32 + jj_; \
            int ci8_ = cc_ * 4 + ks * 2 + hh; \
            bF[ST][ks][nf] = *(const bf16x8*)(ly + (size_t)r_ * 256 + ((ci8_ ^ (r_ & 7)) << 3)); \
        } } }

#define MM(ST) { \
    _Pragma("unroll") for (int ks = 0; ks < 2; ++ks) \
    _Pragma("unroll") for (int mf = 0; mf < 4; ++mf) \
    _Pragma("unroll") for (int nf = 0; nf < 2; ++nf) \
        acc[mf][nf] = __builtin_amdgcn_mfma_f32_32x32x16_bf16( \
            aF[ST][ks][mf], bF[ST][ks][nf], acc[mf][nf], 0, 0, 0); }

    constexpr int NS = KS * 8;
    LOADS(0, 0)
#pragma unroll 1
    for (int sb = 0; sb < NS / 2 - 1; ++sb) {
        const int s0 = sb * 2;
        LOADS(1, s0 + 1)
        MM(0)
        LOADS(0, s0 + 2)
        MM(1)
    }
    LOADS(1, NS - 1)
    MM(0)
    MM(1)
#undef LOADS
#undef MM

    // ---------------- fused epilogue ----------------
    const int tl0 = tq * 64 + l31, tl1 = tl0 + 32;

    // pass 1: gate logits p,q (sum over all 256 co)
    float p0 = 0.f, q0 = 0.f, p1 = 0.f, q1 = 0.f;
#pragma unroll
    for (int mf = 0; mf < 4; ++mf)
#pragma unroll
        for (int r4 = 0; r4 < 4; ++r4) {
            int cb4 = cog * 128 + mf * 32 + r4 * 8 + hh * 4;
            f32x4 f0 = *(const f32x4*)(fc + cb4);
            f32x4 f1 = *(const f32x4*)(fc + 256 + cb4);
#pragma unroll
            for (int qd = 0; qd < 4; ++qd) {
                float a0 = acc[mf][0][r4 * 4 + qd];
                float a1 = acc[mf][1][r4 * 4 + qd];
                p0 += f0[qd] * a0; q0 += f1[qd] * a0;
                p1 += f0[qd] * a1; q1 += f1[qd] * a1;
            }
        }
    p0 += __shfl_xor(p0, 32, 64); q0 += __shfl_xor(q0, 32, 64);
    p1 += __shfl_xor(p1, 32, 64); q1 += __shfl_xor(q1, 32, 64);
    if (!hh) {
        redpq[tl0][cog * 2] = p0; redpq[tl0][cog * 2 + 1] = q0;
        redpq[tl1][cog * 2] = p1; redpq[tl1][cog * 2 + 1] = q1;
    }
    __syncthreads();
    float P0 = p0 + redpq[tl0][(1 - cog) * 2], Q0 = q0 + redpq[tl0][(1 - cog) * 2 + 1];
    float P1 = p1 + redpq[tl1][(1 - cog) * 2], Q1 = q1 + redpq[tl1][(1 - cog) * 2 + 1];
    float sc0 = 0.5f * (P0 + Q0) + 0.1f * fmaxf(P0, Q0);
    float sc1 = 0.5f * (P1 + Q1) + 0.1f * fmaxf(P1, Q1);
    float g0 = 1.0f + 1.0f / (1.0f + expf(-sc0));
    float g1 = 1.0f + 1.0f / (1.0f + expf(-sc1));
    const bool z0 = (LVALID < S_) && (t0 + tl0 >= LVALID);
    const bool z1 = (LVALID < S_) && (t0 + tl1 >= LVALID);

    if constexpr (LAST) {
#pragma unroll
        for (int mf = 0; mf < 4; ++mf)
#pragma unroll
            for (int r4 = 0; r4 < 4; ++r4) {
                int cb4 = cog * 128 + mf * 32 + r4 * 8 + hh * 4;
                f32x4 v0, v1;
#pragma unroll
                for (int qd = 0; qd < 4; ++qd) {
                    v0[qd] = z0 ? 0.0f : acc[mf][0][r4 * 4 + qd] * g0;
                    v1[qd] = z1 ? 0.0f : acc[mf][1][r4 * 4 + qd] * g1;
                }
                *(f32x4*)(fout + ((size_t)(b * S_ + t0 + tl0)) * C_ + cb4) = v0;
                *(f32x4*)(fout + ((size_t)(b * S_ + t0 + tl1)) * C_ + cb4) = v1;
            }
        return;
    }

    // pass 2: gate in place + channel stats for next layer's norm
    float s10 = 0.f, s20 = 0.f, s11 = 0.f, s21 = 0.f;
#pragma unroll
    for (int mf = 0; mf < 4; ++mf)
#pragma unroll
        for (int e = 0; e < 16; ++e) {
            float a0 = acc[mf][0][e] * g0; acc[mf][0][e] = a0; s10 += a0; s20 += a0 * a0;
            float a1 = acc[mf][1][e] * g1; acc[mf][1][e] = a1; s11 += a1; s21 += a1 * a1;
        }
    s10 += __shfl_xor(s10, 32, 64); s20 += __shfl_xor(s20, 32, 64);
    s11 += __shfl_xor(s11, 32, 64); s21 += __shfl_xor(s21, 32, 64);
    if (!hh) {
        redss[tl0][cog * 2] = s10; redss[tl0][cog * 2 + 1] = s20;
        redss[tl1][cog * 2] = s11; redss[tl1][cog * 2 + 1] = s21;
    }
    __syncthreads();
    float S10 = s10 + redss[tl0][(1 - cog) * 2], S20 = s20 + redss[tl0][(1 - cog) * 2 + 1];
    float S11 = s11 + redss[tl1][(1 - cog) * 2], S21 = s21 + redss[tl1][(1 - cog) * 2 + 1];
    float mean0 = S10 * (1.0f / 256.0f);
    float inv0  = rsqrtf(fmaxf((S20 - 256.0f * mean0 * mean0) * (1.0f / 255.0f), 0.0f) + 1e-5f);
    float mean1 = S11 * (1.0f / 256.0f);
    float inv1  = rsqrtf(fmaxf((S21 - 256.0f * mean1 * mean1) * (1.0f / 255.0f), 0.0f) + 1e-5f);

    __hip_bfloat16* yb0 = ynext + ((size_t)(b * SP + 8 + t0 + tl0)) * C_;
    __hip_bfloat16* yb1 = ynext + ((size_t)(b * SP + 8 + t0 + tl1)) * C_;
#pragma unroll
    for (int mf = 0; mf < 4; ++mf)
#pragma unroll
        for (int r4 = 0; r4 < 4; ++r4) {
            int cb4 = cog * 128 + mf * 32 + r4 * 8 + hh * 4;
            f32x4 wv4 = *(const f32x4*)(cwn + cb4);
            f32x4 bv4 = *(const f32x4*)(cbn + cb4);
            union { ushort4 u; __hip_bfloat16 e[4]; } o0, o1;
#pragma unroll
            for (int qd = 0; qd < 4; ++qd) {
                float v0 = z0 ? fmaxf(bv4[qd], 0.f)
                              : fmaxf(0.f, (acc[mf][0][r4 * 4 + qd] - mean0) * inv0 * wv4[qd] + bv4[qd]);
                float v1 = z1 ? fmaxf(bv4[qd], 0.f)
                              : fmaxf(0.f, (acc[mf][1][r4 * 4 + qd] - mean1) * inv1 * wv4[qd] + bv4[qd]);
                o0.e[qd] = __float2bfloat16(v0);
                o1.e[qd] = __float2bfloat16(v1);
            }
            *(ushort4*)(yb0 + cb4) = o0.u;
            *(ushort4*)(yb1 + cb4) = o1.u;
        }
}

// ---------------------------------------------------------------------------
extern "C" void kernel_launch(void* const* d_in, const int* in_sizes, int n_in,
                              void* d_out, int out_size, void* d_ws, size_t ws_size,
                              hipStream_t stream) {
    const float* inputs = (const float*)d_in[0];
    const float* cw[5] = { (const float*)d_in[1],  (const float*)d_in[4],
                           (const float*)d_in[7],  (const float*)d_in[10],
                           (const float*)d_in[13] };
    const float* cb[5] = { (const float*)d_in[2],  (const float*)d_in[5],
                           (const float*)d_in[8],  (const float*)d_in[11],
                           (const float*)d_in[14] };
    const float* Wf[5] = { (const float*)d_in[3],  (const float*)d_in[6],
                           (const float*)d_in[9],  (const float*)d_in[12],
                           (const float*)d_in[15] };
    const float* fc = (const float*)d_in[16];

    char* ws = (char*)d_ws;
    __hip_bfloat16* yP = (__hip_bfloat16*)ws;                    // 17,039,360 B
    __hip_bfloat16* yQ = (__hip_bfloat16*)(ws + 17039360);       // 17,039,360 B
    __hip_bfloat16* wb = (__hip_bfloat16*)(ws + 34078720);       // 3,932,160 B
    float* out = (float*)d_out;

    wcvt_all<<<7680, 256, 0, stream>>>(Wf[0], Wf[1], Wf[2], Wf[3], Wf[4], wb);
    zeroh_kernel<<<64, 256, 0, stream>>>(yQ);
    prep0_kernel<<<4160, 256, 0, stream>>>(inputs, cw[0], cb[0], yP);

    conv_fused<4, 1, 1023, false><<<256, 256, 0, stream>>>(yP, wb,           yQ, nullptr, fc, cw[1], cb[1]);
    conv_fused<5, 2, 1024, false><<<256, 256, 0, stream>>>(yQ, wb +  262144, yP, nullptr, fc, cw[2], cb[2]);
    conv_fused<6, 2, 1023, false><<<256, 256, 0, stream>>>(yP, wb +  589824, yQ, nullptr, fc, cw[3], cb[3]);
    conv_fused<7, 3, 1024, false><<<256, 256, 0, stream>>>(yQ, wb +  983040, yP, nullptr, fc, cw[4], cb[4]);
    conv_fused<8, 3, 1023, true ><<<256, 256, 0, stream>>>(yP, wb + 1441792, nullptr, out, fc, nullptr, nullptr);
}

// Round 7
// 310.562 us; speedup vs baseline: 1.3099x; 1.2347x over previous
//
#include <hip/hip_runtime.h>
#include <hip/hip_bf16.h>

#define B_ 32
#define S_ 1024
#define C_ 256
#define SP 1040   // 8 left halo + 1024 + 8 right halo rows per batch

typedef float f32x4  __attribute__((ext_vector_type(4)));
typedef float f32x16 __attribute__((ext_vector_type(16)));
typedef __bf16 bf16x8 __attribute__((ext_vector_type(8)));

// ---------------------------------------------------------------------------
// Repack all 5 layers' W[co][ci][k] fp32 -> bf16, contiguous dst.
// dst bits (within layer): e=i&7, co=(i>>3)&255, hh=(i>>11)&1, ks=(i>>12)&1,
// c32=(i>>13)&7, j=i>>16;  ci = c32*32+ks*16+hh*8+e
// A-frag load (lane, step s=j*8+c32): 16B at (s*4 + ks*2 + hh)*2048 + co*8
// ---------------------------------------------------------------------------
__global__ __launch_bounds__(256) void wcvt_all(
        const float* __restrict__ w4, const float* __restrict__ w5,
        const float* __restrict__ w6, const float* __restrict__ w7,
        const float* __restrict__ w8, __hip_bfloat16* __restrict__ wb) {
    int i = blockIdx.x * 256 + threadIdx.x;   // grid exact: 1966080 / 256
    const float* src; int base, k;
    if      (i <  262144) { src = w4; base = 0;       k = 4; }
    else if (i <  589824) { src = w5; base = 262144;  k = 5; }
    else if (i <  983040) { src = w6; base = 589824;  k = 6; }
    else if (i < 1441792) { src = w7; base = 983040;  k = 7; }
    else                  { src = w8; base = 1441792; k = 8; }
    int ii = i - base;
    int e = ii & 7, co = (ii >> 3) & 255, hh = (ii >> 11) & 1;
    int ks = (ii >> 12) & 1, c32 = (ii >> 13) & 7, j = ii >> 16;
    int ci = c32 * 32 + ks * 16 + hh * 8 + e;
    wb[i] = __float2bfloat16(src[(co * 256 + ci) * k + j]);
}

// Zero the 16 halo rows of a haloed y buffer (32 b x 16 rows x 256 ch).
__global__ __launch_bounds__(256) void zeroh_kernel(__hip_bfloat16* __restrict__ y) {
    int i = blockIdx.x * 256 + threadIdx.x;   // 16384 threads
    int b = i >> 9, rr = (i >> 5) & 15, s = i & 31;
    int row = (rr < 8) ? rr : (1024 + rr);    // 0..7, 1032..1039
    uint4 z = make_uint4(0, 0, 0, 0);
    *(uint4*)(y + ((size_t)(b * SP + row)) * C_ + s * 8) = z;
}

// ---------------------------------------------------------------------------
// prep0: ChannelNorm + ReLU on fp32 input -> bf16 haloed y. 2 rows/wave,
// 32 lanes x 8ch per row; 5-level shfl reduce (stays within 32-lane half).
// ---------------------------------------------------------------------------
__global__ __launch_bounds__(256) void prep0_kernel(const float* __restrict__ in,
                                                    const float* __restrict__ cw,
                                                    const float* __restrict__ cb,
                                                    __hip_bfloat16* __restrict__ yout) {
    const int lane = threadIdx.x & 63;
    const int sl   = lane & 31;
    const int rid  = (blockIdx.x * 4 + (threadIdx.x >> 6)) * 2 + (lane >> 5);
    const int b = rid / SP;
    const int t = (rid - b * SP) - 8;
    __hip_bfloat16* drow = yout + (size_t)rid * C_ + sl * 8;
    if (t < 0 || t >= S_) { *(uint4*)drow = make_uint4(0, 0, 0, 0); return; }

    const float* row = in + ((size_t)(b * S_ + t)) * C_ + sl * 8;
    f32x4 x0 = *(const f32x4*)row;
    f32x4 x1 = *(const f32x4*)(row + 4);
    float s1 = x0.x + x0.y + x0.z + x0.w + x1.x + x1.y + x1.z + x1.w;
    float s2 = x0.x*x0.x + x0.y*x0.y + x0.z*x0.z + x0.w*x0.w
             + x1.x*x1.x + x1.y*x1.y + x1.z*x1.z + x1.w*x1.w;
#pragma unroll
    for (int m = 16; m >= 1; m >>= 1) {
        s1 += __shfl_xor(s1, m, 64);
        s2 += __shfl_xor(s2, m, 64);
    }
    float mean = s1 * (1.0f / 256.0f);
    float var  = fmaxf((s2 - 256.0f * mean * mean) * (1.0f / 255.0f), 0.0f);
    float inv  = rsqrtf(var + 1e-5f);
    f32x4 w0 = *(const f32x4*)(cw + sl * 8);
    f32x4 w1 = *(const f32x4*)(cw + sl * 8 + 4);
    f32x4 b0 = *(const f32x4*)(cb + sl * 8);
    f32x4 b1 = *(const f32x4*)(cb + sl * 8 + 4);
    union { uint4 u; __hip_bfloat16 e[8]; } o;
    o.e[0] = __float2bfloat16(fmaxf(0.f, (x0.x - mean)*inv*w0.x + b0.x));
    o.e[1] = __float2bfloat16(fmaxf(0.f, (x0.y - mean)*inv*w0.y + b0.y));
    o.e[2] = __float2bfloat16(fmaxf(0.f, (x0.z - mean)*inv*w0.z + b0.z));
    o.e[3] = __float2bfloat16(fmaxf(0.f, (x0.w - mean)*inv*w0.w + b0.w));
    o.e[4] = __float2bfloat16(fmaxf(0.f, (x1.x - mean)*inv*w1.x + b1.x));
    o.e[5] = __float2bfloat16(fmaxf(0.f, (x1.y - mean)*inv*w1.y + b1.y));
    o.e[6] = __float2bfloat16(fmaxf(0.f, (x1.z - mean)*inv*w1.z + b1.z));
    o.e[7] = __float2bfloat16(fmaxf(0.f, (x1.w - mean)*inv*w1.w + b1.w));
    *(uint4*)drow = o.u;
}

// ---------------------------------------------------------------------------
// conv_fused v5: block = 4 waves (256 thr) = 4 co-groups; tile 256co x 32t.
// Wave = 64co x 32t (mf=2, nf=1), mfma_f32_32x32x16_bf16, 2-stage pipeline.
// Grid = 32 b x 32 tt = 1024 blocks; __launch_bounds__(256,4) -> <=128 VGPR,
// 4 blocks/CU = 16 waves/CU = 4 waves/SIMD (fixes v4's naked-latency 1/SIMD).
// Epilogue: fused gate + next-layer channel-norm; output staged in LDS
// (padded stride) then copied out coalesced (fixes v4's 3.3x write amp).
// ---------------------------------------------------------------------------
template<int KS, int PAD, int LVALID, bool LAST>
__global__ __launch_bounds__(256, 4) void conv_fused(
        const __hip_bfloat16* __restrict__ y,
        const __hip_bfloat16* __restrict__ wb,
        __hip_bfloat16* __restrict__ ynext,
        float* __restrict__ fout,
        const float* __restrict__ fc,
        const float* __restrict__ cwn,
        const float* __restrict__ cbn) {
    __shared__ alignas(16) __hip_bfloat16 ly[39 * 256];   // 19,968 B (K-loop B; reused as out-stage)
    __shared__ float redpq[4][32][2];
    __shared__ float redss[4][32][2];
    const int tid  = threadIdx.x;
    const int lane = tid & 63;
    const int cog  = tid >> 6;               // wave = co-group
    const int tt   = blockIdx.x & 31;
    const int b    = blockIdx.x >> 5;
    const int t0   = tt << 5;
    const int l31  = lane & 31;
    const int hh   = lane >> 5;

    // stage RSTG rows x 256 ci (padded rows t0-PAD .. ), swizzle slot ^(r&7)
    constexpr int RSTG  = 32 + KS - 1;
    constexpr int UNITS = RSTG * 32;         // 16B units
    {
        const __hip_bfloat16* yb = y + ((size_t)(b * SP + 8 + t0 - PAD)) * C_;
#pragma unroll
        for (int c = 0; c < (UNITS + 255) / 256; ++c) {
            int u = c * 256 + tid;
            if (u < UNITS) {
                int r = u >> 5, s2 = u & 31;
                *(bf16x8*)(ly + (size_t)u * 8) =
                    *(const bf16x8*)(yb + (size_t)r * C_ + ((s2 ^ (r & 7)) << 3));
            }
        }
    }
    __syncthreads();

    f32x16 acc[2];
#pragma unroll
    for (int mf = 0; mf < 2; ++mf)
#pragma unroll
        for (int e = 0; e < 16; ++e)
            acc[mf][e] = 0.0f;

    const __hip_bfloat16* abase = wb + (size_t)hh * 2048 + (size_t)(cog * 64 + l31) * 8;

    bf16x8 aF[2][2][2], bF[2][2];

#define LOADS(ST, S) { \
    const int jj_ = (S) >> 3, cc_ = (S) & 7; \
    _Pragma("unroll") for (int ks = 0; ks < 2; ++ks) { \
        _Pragma("unroll") for (int mf = 0; mf < 2; ++mf) \
            aF[ST][ks][mf] = *(const bf16x8*)(abase + (size_t)((S) * 4 + ks * 2) * 2048 + mf * 256); \
        { int r_ = l31 + jj_; \
          int ci8_ = cc_ * 4 + ks * 2 + hh; \
          bF[ST][ks] = *(const bf16x8*)(ly + (size_t)r_ * 256 + ((ci8_ ^ (r_ & 7)) << 3)); } \
    } }

#define MM(ST) { \
    _Pragma("unroll") for (int ks = 0; ks < 2; ++ks) \
    _Pragma("unroll") for (int mf = 0; mf < 2; ++mf) \
        acc[mf] = __builtin_amdgcn_mfma_f32_32x32x16_bf16( \
            aF[ST][ks][mf], bF[ST][ks], acc[mf], 0, 0, 0); }

    constexpr int NS = KS * 8;
    LOADS(0, 0)
#pragma unroll 1
    for (int sb = 0; sb < NS / 2 - 1; ++sb) {
        const int s0 = sb * 2;
        LOADS(1, s0 + 1)
        MM(0)
        LOADS(0, s0 + 2)
        MM(1)
    }
    LOADS(1, NS - 1)
    MM(0)
    MM(1)
#undef LOADS
#undef MM

    // ---------------- fused epilogue ----------------
    // acc layout: col = lane&31 -> t (t0+l31); row = (reg&3)+8*(reg>>2)+4*hh
    // -> co = cog*64 + mf*32 + r4*8 + hh*4 + qd
    const int t = l31;

    // pass 1: gate logits p,q (sum over all 256 co)
    float p = 0.f, q = 0.f;
#pragma unroll
    for (int mf = 0; mf < 2; ++mf)
#pragma unroll
        for (int r4 = 0; r4 < 4; ++r4) {
            int cb4 = cog * 64 + mf * 32 + r4 * 8 + hh * 4;
            f32x4 f0 = *(const f32x4*)(fc + cb4);
            f32x4 f1 = *(const f32x4*)(fc + 256 + cb4);
#pragma unroll
            for (int qd = 0; qd < 4; ++qd) {
                float a = acc[mf][r4 * 4 + qd];
                p += f0[qd] * a; q += f1[qd] * a;
            }
        }
    p += __shfl_xor(p, 32, 64); q += __shfl_xor(q, 32, 64);
    if (!hh) { redpq[cog][t][0] = p; redpq[cog][t][1] = q; }
    __syncthreads();
    float P = redpq[0][t][0] + redpq[1][t][0] + redpq[2][t][0] + redpq[3][t][0];
    float Q = redpq[0][t][1] + redpq[1][t][1] + redpq[2][t][1] + redpq[3][t][1];
    float sc = 0.5f * (P + Q) + 0.1f * fmaxf(P, Q);
    float g  = 1.0f + 1.0f / (1.0f + expf(-sc));
    const bool z = (LVALID < S_) && (t0 + t >= LVALID);

    if constexpr (LAST) {
        // stage fp32 out in LDS (16 rows/pass), then coalesced copy-out
        float* lof = (float*)ly;             // [16][260] = 16,640 B
#pragma unroll
        for (int pass = 0; pass < 2; ++pass) {
            __syncthreads();
            if ((t >> 4) == pass) {
                int rr = t & 15;
#pragma unroll
                for (int mf = 0; mf < 2; ++mf)
#pragma unroll
                    for (int r4 = 0; r4 < 4; ++r4) {
                        int cb4 = cog * 64 + mf * 32 + r4 * 8 + hh * 4;
                        f32x4 v;
#pragma unroll
                        for (int qd = 0; qd < 4; ++qd)
                            v[qd] = z ? 0.0f : acc[mf][r4 * 4 + qd] * g;
                        *(f32x4*)(lof + rr * 260 + cb4) = v;
                    }
            }
            __syncthreads();
#pragma unroll
            for (int c = 0; c < 4; ++c) {
                int u = c * 256 + tid;           // 16 rows x 64 16B-units
                int row = u >> 6, c4 = u & 63;
                *(f32x4*)(fout + ((size_t)(b * S_ + t0 + pass * 16 + row)) * C_ + c4 * 4) =
                    *(const f32x4*)(lof + row * 260 + c4 * 4);
            }
        }
        return;
    }

    // pass 2: gate in place + channel stats for next layer's norm
    float s1 = 0.f, s2 = 0.f;
#pragma unroll
    for (int mf = 0; mf < 2; ++mf)
#pragma unroll
        for (int e = 0; e < 16; ++e) {
            float a = acc[mf][e] * g; acc[mf][e] = a; s1 += a; s2 += a * a;
        }
    s1 += __shfl_xor(s1, 32, 64); s2 += __shfl_xor(s2, 32, 64);
    if (!hh) { redss[cog][t][0] = s1; redss[cog][t][1] = s2; }
    __syncthreads();
    float S1 = redss[0][t][0] + redss[1][t][0] + redss[2][t][0] + redss[3][t][0];
    float S2 = redss[0][t][1] + redss[1][t][1] + redss[2][t][1] + redss[3][t][1];
    float mean = S1 * (1.0f / 256.0f);
    float inv  = rsqrtf(fmaxf((S2 - 256.0f * mean * mean) * (1.0f / 255.0f), 0.0f) + 1e-5f);

    // norm + relu -> bf16 staged in LDS [32][264] (padded stride), then copy-out
    __hip_bfloat16* lo = ly;                 // 32*264*2 = 16,896 B <= 19,968
#pragma unroll
    for (int mf = 0; mf < 2; ++mf)
#pragma unroll
        for (int r4 = 0; r4 < 4; ++r4) {
            int cb4 = cog * 64 + mf * 32 + r4 * 8 + hh * 4;
            f32x4 wv4 = *(const f32x4*)(cwn + cb4);
            f32x4 bv4 = *(const f32x4*)(cbn + cb4);
            union { ushort4 u; __hip_bfloat16 e[4]; } o;
#pragma unroll
            for (int qd = 0; qd < 4; ++qd) {
                float v = z ? fmaxf(bv4[qd], 0.f)
                            : fmaxf(0.f, (acc[mf][r4 * 4 + qd] - mean) * inv * wv4[qd] + bv4[qd]);
                o.e[qd] = __float2bfloat16(v);
            }
            *(ushort4*)(lo + t * 264 + cb4) = o.u;
        }
    __syncthreads();
#pragma unroll
    for (int c = 0; c < 4; ++c) {
        int u = c * 256 + tid;               // 32 rows x 32 16B-units
        int row = u >> 5, c16 = u & 31;
        *(bf16x8*)(ynext + ((size_t)(b * SP + 8 + t0 + row)) * C_ + c16 * 8) =
            *(const bf16x8*)(lo + row * 264 + c16 * 8);
    }
}

// ---------------------------------------------------------------------------
extern "C" void kernel_launch(void* const* d_in, const int* in_sizes, int n_in,
                              void* d_out, int out_size, void* d_ws, size_t ws_size,
                              hipStream_t stream) {
    const float* inputs = (const float*)d_in[0];
    const float* cw[5] = { (const float*)d_in[1],  (const float*)d_in[4],
                           (const float*)d_in[7],  (const float*)d_in[10],
                           (const float*)d_in[13] };
    const float* cb[5] = { (const float*)d_in[2],  (const float*)d_in[5],
                           (const float*)d_in[8],  (const float*)d_in[11],
                           (const float*)d_in[14] };
    const float* Wf[5] = { (const float*)d_in[3],  (const float*)d_in[6],
                           (const float*)d_in[9],  (const float*)d_in[12],
                           (const float*)d_in[15] };
    const float* fc = (const float*)d_in[16];

    char* ws = (char*)d_ws;
    __hip_bfloat16* yP = (__hip_bfloat16*)ws;                    // 17,039,360 B
    __hip_bfloat16* yQ = (__hip_bfloat16*)(ws + 17039360);       // 17,039,360 B
    __hip_bfloat16* wb = (__hip_bfloat16*)(ws + 34078720);       // 3,932,160 B
    float* out = (float*)d_out;

    wcvt_all<<<7680, 256, 0, stream>>>(Wf[0], Wf[1], Wf[2], Wf[3], Wf[4], wb);
    zeroh_kernel<<<64, 256, 0, stream>>>(yQ);
    prep0_kernel<<<4160, 256, 0, stream>>>(inputs, cw[0], cb[0], yP);

    conv_fused<4, 1, 1023, false><<<1024, 256, 0, stream>>>(yP, wb,           yQ, nullptr, fc, cw[1], cb[1]);
    conv_fused<5, 2, 1024, false><<<1024, 256, 0, stream>>>(yQ, wb +  262144, yP, nullptr, fc, cw[2], cb[2]);
    conv_fused<6, 2, 1023, false><<<1024, 256, 0, stream>>>(yP, wb +  589824, yQ, nullptr, fc, cw[3], cb[3]);
    conv_fused<7, 3, 1024, false><<<1024, 256, 0, stream>>>(yQ, wb +  983040, yP, nullptr, fc, cw[4], cb[4]);
    conv_fused<8, 3, 1023, true ><<<1024, 256, 0, stream>>>(yP, wb + 1441792, nullptr, out, fc, nullptr, nullptr);
}